// Round 3
// baseline (220.900 us; speedup 1.0000x reference)
//
#include <hip/hip_runtime.h>

constexpr int NKD = 64;    // node key dim
constexpr int EKD = 16;    // edge key dim
constexpr int QD  = 80;    // NKD + EKD
constexpr int NN  = 256;   // sequence length
constexpr int DVD = 64;    // value dim
constexpr int BB  = 4;
constexpr int HH  = 8;
constexpr int QT  = 8;     // q rows per block
constexpr int NT  = 256;   // threads per block

// Grid: 32 (b,h) x 32 q-tiles = 1024 blocks (4/CU), 256 threads (4 waves).
__global__ __launch_bounds__(256, 4) void sdpe_kernel(
    const float* __restrict__ q, const float* __restrict__ nk,
    const float* __restrict__ ek, const float* __restrict__ v,
    const int* __restrict__ mask, float* __restrict__ out, float* __restrict__ attn_out)
{
    const int bid  = blockIdx.x;
    const int bh   = bid >> 5;            // NN/QT = 32 tiles per (b,h)
    const int q0   = (bid & 31) * QT;
    const int b    = bh >> 3;             // H == 8
    const int tid  = threadIdx.x;
    const int wave = tid >> 6;
    const int lane = tid & 63;

    __shared__ float s_q[QT * QD];        // 2.5 KB
    __shared__ float s_S[QT * NN];        // 8 KB   scores -> attn in place
    __shared__ float s_nk[64 * 64];       // 16 KB  xor-swizzled nk tile

    // ---- stage q tile (coalesced) ----
    {
        const float4* src = (const float4*)(q + ((size_t)bh * NN + q0) * QD);
        if (tid < QT * QD / 4) ((float4*)s_q)[tid] = src[tid];
    }
    __syncthreads();

    // ---- phase 1: edge scores — flat contiguous float4 stream (134 MB, read once) ----
    // flat f4 index within row-block: f = k*4 + jb  ->  thread t covers jb=t&3,
    // k = (t>>2) + 64*i for i in 0..3. Quad shuffle sums the 4 jb partials.
    {
        const int jb = tid & 3;
        const int kb = tid >> 2;          // 0..63
        const float4* ekb = (const float4*)ek + ((size_t)bh * NN + q0) * (NN * EKD / 4);
        #pragma unroll 2
        for (int r = 0; r < QT; ++r) {
            const float4 qe4 = *(const float4*)&s_q[r * QD + NKD + jb * 4];
            const float4 e0 = ekb[(size_t)r * 1024 + tid];
            const float4 e1 = ekb[(size_t)r * 1024 + tid + 256];
            const float4 e2 = ekb[(size_t)r * 1024 + tid + 512];
            const float4 e3 = ekb[(size_t)r * 1024 + tid + 768];
            float p0 = e0.x*qe4.x + e0.y*qe4.y + e0.z*qe4.z + e0.w*qe4.w;
            float p1 = e1.x*qe4.x + e1.y*qe4.y + e1.z*qe4.z + e1.w*qe4.w;
            float p2 = e2.x*qe4.x + e2.y*qe4.y + e2.z*qe4.z + e2.w*qe4.w;
            float p3 = e3.x*qe4.x + e3.y*qe4.y + e3.z*qe4.z + e3.w*qe4.w;
            p0 += __shfl_xor(p0, 1);  p0 += __shfl_xor(p0, 2);
            p1 += __shfl_xor(p1, 1);  p1 += __shfl_xor(p1, 2);
            p2 += __shfl_xor(p2, 1);  p2 += __shfl_xor(p2, 2);
            p3 += __shfl_xor(p3, 1);  p3 += __shfl_xor(p3, 2);
            // lane with sub-index jb writes k = kb + 64*jb (static select, no scratch)
            const float pw = (jb == 0) ? p0 : (jb == 1) ? p1 : (jb == 2) ? p2 : p3;
            s_S[r * NN + kb + 64 * jb] = pw;
        }
    }
    __syncthreads();

    // ---- phase 2: node scores via LDS-staged xor-swizzled nk tiles ----
    // wave w computes rows {w, w+4}; lane = local k in tile.
    for (int kt = 0; kt < 4; ++kt) {
        {
            const float4* src = (const float4*)nk + ((size_t)bh * NN + kt * 64) * (NKD / 4);
            #pragma unroll
            for (int i = 0; i < 4; ++i) {
                const int f   = tid + 256 * i;       // f4 idx 0..1023
                const int row = f >> 4, c4 = f & 15;
                *(float4*)&s_nk[row * 64 + ((c4 ^ (row & 7)) << 2)] = src[f];
            }
        }
        __syncthreads();
        float acc0 = 0.f, acc1 = 0.f;
        #pragma unroll
        for (int j4 = 0; j4 < 16; ++j4) {
            const float4 n4 = *(const float4*)&s_nk[lane * 64 + ((j4 ^ (lane & 7)) << 2)];
            const float4 qa = *(const float4*)&s_q[wave * QD + j4 * 4];
            const float4 qb = *(const float4*)&s_q[(wave + 4) * QD + j4 * 4];
            acc0 += n4.x*qa.x + n4.y*qa.y + n4.z*qa.z + n4.w*qa.w;
            acc1 += n4.x*qb.x + n4.y*qb.y + n4.z*qb.z + n4.w*qb.w;
        }
        const int kg = kt * 64 + lane;
        s_S[wave * NN + kg]       += acc0;
        s_S[(wave + 4) * NN + kg] += acc1;
        __syncthreads();
    }

    // ---- phase 3: softmax — wave w handles rows {w, w+4} ----
    #pragma unroll
    for (int rr = 0; rr < 2; ++rr) {
        const int r = wave + rr * 4;
        const size_t rowg = (size_t)bh * NN + q0 + r;
        float4 f = *(const float4*)&s_S[r * NN + lane * 4];
        const int4 m4 = *(const int4*)(mask + ((size_t)b * NN + q0 + r) * NN + lane * 4);
        f.x = (m4.x == 0) ? -1e9f : f.x * 0.125f;
        f.y = (m4.y == 0) ? -1e9f : f.y * 0.125f;
        f.z = (m4.z == 0) ? -1e9f : f.z * 0.125f;
        f.w = (m4.w == 0) ? -1e9f : f.w * 0.125f;
        float mx = fmaxf(fmaxf(f.x, f.y), fmaxf(f.z, f.w));
        #pragma unroll
        for (int o = 32; o >= 1; o >>= 1) mx = fmaxf(mx, __shfl_xor(mx, o));
        float4 e;
        e.x = __expf(f.x - mx); e.y = __expf(f.y - mx);
        e.z = __expf(f.z - mx); e.w = __expf(f.w - mx);
        float s = e.x + e.y + e.z + e.w;
        #pragma unroll
        for (int o = 32; o >= 1; o >>= 1) s += __shfl_xor(s, o);
        const float inv = 1.f / s;
        e.x *= inv; e.y *= inv; e.z *= inv; e.w *= inv;
        *(float4*)&s_S[r * NN + lane * 4] = e;
        *(float4*)(attn_out + rowg * NN + lane * 4) = e;   // coalesced 1KB/wave
    }
    __syncthreads();

    // ---- phase 4: PV — wave w rows {w, w+4}; lane = (kq, d4); b128 attn reads ----
    {
        const int d4 = lane & 15;
        const int kq = lane >> 4;
        float4 a0 = make_float4(0.f,0.f,0.f,0.f), a1 = make_float4(0.f,0.f,0.f,0.f);
        const float* vb = v + (size_t)bh * NN * DVD + d4 * 4;
        #pragma unroll 4
        for (int i = 0; i < 16; ++i) {
            const int k0 = i * 16 + kq * 4;
            const float4 w0 = *(const float4*)&s_S[wave * NN + k0];
            const float4 w1 = *(const float4*)&s_S[(wave + 4) * NN + k0];
            const float4 v0 = *(const float4*)(vb + (size_t)(k0 + 0) * DVD);
            const float4 v1 = *(const float4*)(vb + (size_t)(k0 + 1) * DVD);
            const float4 v2 = *(const float4*)(vb + (size_t)(k0 + 2) * DVD);
            const float4 v3 = *(const float4*)(vb + (size_t)(k0 + 3) * DVD);
            a0.x += w0.x*v0.x + w0.y*v1.x + w0.z*v2.x + w0.w*v3.x;
            a0.y += w0.x*v0.y + w0.y*v1.y + w0.z*v2.y + w0.w*v3.y;
            a0.z += w0.x*v0.z + w0.y*v1.z + w0.z*v2.z + w0.w*v3.z;
            a0.w += w0.x*v0.w + w0.y*v1.w + w0.z*v2.w + w0.w*v3.w;
            a1.x += w1.x*v0.x + w1.y*v1.x + w1.z*v2.x + w1.w*v3.x;
            a1.y += w1.x*v0.y + w1.y*v1.y + w1.z*v2.y + w1.w*v3.y;
            a1.z += w1.x*v0.z + w1.y*v1.z + w1.z*v2.z + w1.w*v3.z;
            a1.w += w1.x*v0.w + w1.y*v1.w + w1.z*v2.w + w1.w*v3.w;
        }
        a0.x += __shfl_xor(a0.x, 16); a0.y += __shfl_xor(a0.y, 16);
        a0.z += __shfl_xor(a0.z, 16); a0.w += __shfl_xor(a0.w, 16);
        a1.x += __shfl_xor(a1.x, 16); a1.y += __shfl_xor(a1.y, 16);
        a1.z += __shfl_xor(a1.z, 16); a1.w += __shfl_xor(a1.w, 16);
        a0.x += __shfl_xor(a0.x, 32); a0.y += __shfl_xor(a0.y, 32);
        a0.z += __shfl_xor(a0.z, 32); a0.w += __shfl_xor(a0.w, 32);
        a1.x += __shfl_xor(a1.x, 32); a1.y += __shfl_xor(a1.y, 32);
        a1.z += __shfl_xor(a1.z, 32); a1.w += __shfl_xor(a1.w, 32);
        if (kq == 0) {
            const size_t rowg0 = (size_t)bh * NN + q0 + wave;
            *(float4*)(out + rowg0 * DVD + d4 * 4)       = a0;
            *(float4*)(out + (rowg0 + 4) * DVD + d4 * 4) = a1;
        }
    }
}

extern "C" void kernel_launch(void* const* d_in, const int* in_sizes, int n_in,
                              void* d_out, int out_size, void* d_ws, size_t ws_size,
                              hipStream_t stream) {
    const float* q    = (const float*)d_in[0];
    const float* nk   = (const float*)d_in[1];
    const float* ek   = (const float*)d_in[2];
    const float* v    = (const float*)d_in[3];
    const int*   mask = (const int*)d_in[4];

    float* out      = (float*)d_out;
    float* attn_out = out + (size_t)BB * HH * NN * DVD;   // tuple: (output, attn)

    const int nblocks = BB * HH * (NN / QT);   // 1024
    sdpe_kernel<<<nblocks, NT, 0, stream>>>(q, nk, ek, v, mask, out, attn_out);
}